// Round 6
// baseline (1144.535 us; speedup 1.0000x reference)
//
#include <hip/hip_runtime.h>
#include <hip/hip_bf16.h>
#include <stdint.h>

#define M_NODES 100000
#define NE      300000
#define D       256
#define D2      512
#define NLAYERS 4

#define SPMM_TPB  1024
#define SPMM_GRID (M_NODES / (2 * (SPMM_TPB / 64)))   // 3125 blocks, 1 row-pair per wave

typedef float  f32x4  __attribute__((ext_vector_type(4)));
typedef __bf16 bf16x8 __attribute__((ext_vector_type(8)));

static __device__ __forceinline__ float bf2f(uint32_t u) {
  union { uint32_t i; float f; } v; v.i = u << 16; return v.f;
}
static __device__ __forceinline__ uint32_t f2bf(float f) {
  union { float f; uint32_t i; } v; v.f = f;
  return (v.i + 0x7fffu + ((v.i >> 16) & 1u)) >> 16;
}
static __device__ __forceinline__ void gload_lds16(const void* g, void* l) {
  __builtin_amdgcn_global_load_lds((const __attribute__((address_space(1))) uint32_t*)g,
                                   (__attribute__((address_space(3))) uint32_t*)l, 16, 0, 0);
}

// ---------------- CSR build ----------------
__global__ void hist_kernel(const int* __restrict__ rows, int* __restrict__ counts) {
  int e = blockIdx.x * 256 + threadIdx.x;
  if (e < NE) atomicAdd(&counts[rows[e]], 1);
}

__global__ void scan1_kernel(const int* __restrict__ counts, int* __restrict__ rp,
                             int* __restrict__ bsum) {
  __shared__ int sd[256];
  int tid = threadIdx.x;
  int base = blockIdx.x * 1024 + tid * 4;
  int v0 = (base + 0 < M_NODES) ? counts[base + 0] : 0;
  int v1 = (base + 1 < M_NODES) ? counts[base + 1] : 0;
  int v2 = (base + 2 < M_NODES) ? counts[base + 2] : 0;
  int v3 = (base + 3 < M_NODES) ? counts[base + 3] : 0;
  int tsum = v0 + v1 + v2 + v3;
  sd[tid] = tsum; __syncthreads();
  for (int off = 1; off < 256; off <<= 1) {
    int x = sd[tid];
    if (tid >= off) x += sd[tid - off];
    __syncthreads(); sd[tid] = x; __syncthreads();
  }
  int excl = sd[tid] - tsum;
  if (base + 0 < M_NODES) rp[base + 0] = excl; excl += v0;
  if (base + 1 < M_NODES) rp[base + 1] = excl; excl += v1;
  if (base + 2 < M_NODES) rp[base + 2] = excl; excl += v2;
  if (base + 3 < M_NODES) rp[base + 3] = excl;
  if (tid == 255) bsum[blockIdx.x] = sd[255];
}

__global__ void scan2_kernel(const int* __restrict__ bsum, int* __restrict__ boff) {
  __shared__ int sd[128];
  int tid = threadIdx.x;
  int v = (tid < 98) ? bsum[tid] : 0;
  sd[tid] = v; __syncthreads();
  for (int off = 1; off < 128; off <<= 1) {
    int x = sd[tid];
    if (tid >= off) x += sd[tid - off];
    __syncthreads(); sd[tid] = x; __syncthreads();
  }
  if (tid < 98) boff[tid] = sd[tid] - v;
}

__global__ void scan3_kernel(int* __restrict__ rp, const int* __restrict__ boff,
                             int* __restrict__ cursor) {
  int i = blockIdx.x * 256 + threadIdx.x;
  if (i > M_NODES) return;
  int v = (i < M_NODES) ? rp[i] + boff[i >> 10] : NE;
  rp[i] = v;
  if (i < M_NODES) cursor[i] = v;
}

// emeta[p] = { col, val bits } — interleaved so spmm does ONE metadata load.
__global__ void scatter_kernel(const int* __restrict__ rows, const int* __restrict__ cols,
                               const float* __restrict__ vals, int* __restrict__ cursor,
                               uint2* __restrict__ emeta) {
  int e = blockIdx.x * 256 + threadIdx.x;
  if (e >= NE) return;
  int r = rows[e];
  int p = atomicAdd(&cursor[r], 1);
  uint2 m; m.x = (uint32_t)cols[e]; m.y = __float_as_uint(vals[e]);
  emeta[p] = m;
}

// ---------------- x prep: bf16 h + f32 copy into out right half ----------------
__global__ void prep_x_kernel(const float* __restrict__ x, ushort* __restrict__ h,
                              float* __restrict__ out) {
  size_t idx = (size_t)blockIdx.x * 256 + threadIdx.x;  // M*D/4 threads
  size_t i = idx >> 6; int c = (int)(idx & 63) * 4;
  float4 v = *(const float4*)(x + i * D + c);
  *(float4*)(out + i * D2 + D + c) = v;
  ushort4 o;
  o.x = (ushort)f2bf(v.x); o.y = (ushort)f2bf(v.y);
  o.z = (ushort)f2bf(v.z); o.w = (ushort)f2bf(v.w);
  *(ushort4*)(h + i * D + c) = o;
}

// Bt[layer][n][k] = bf16( n<256 ? W[layer][k][n] : SW[layer][k][n-256] )
__global__ void conv_w_kernel(const float* __restrict__ W, const float* __restrict__ SW,
                              ushort* __restrict__ Bt) {
  int idx = blockIdx.x * 256 + threadIdx.x;  // 4*512*256 = 524288
  if (idx >= NLAYERS * D2 * D) return;
  int k = idx & (D - 1);
  int n = (idx >> 8) & (D2 - 1);
  int layer = idx >> 17;
  float v = (n < D) ? W[(size_t)layer * D * D + k * D + n]
                    : SW[(size_t)layer * D * D + k * D + (n - D)];
  Bt[idx] = (ushort)f2bf(v);
}

// ---------------- GEMM: [M,256](bf16) x [256,512](bf16, N-major) -> AB [M,512](bf16) ----------------
#define BM 128
#define BN 128
#define BK 64

__global__ __launch_bounds__(256, 2)
void gemm_kernel(const ushort* __restrict__ h, const ushort* __restrict__ Bt,
                 ushort* __restrict__ outAB) {
  __shared__ __align__(16) ushort As[BM * BK];  // [128][64], row = 128B
  __shared__ __align__(16) ushort Bs[BN * BK];  // [128 n][64 k]
  const int tid = threadIdx.x;
  const int m0 = blockIdx.x * BM;
  const int n0 = blockIdx.y * BN;
  const int wv = tid >> 6, l = tid & 63;
  const int wr = wv >> 1, wc = wv & 1;
  const int lrow = l & 15, lhi = l >> 4;

  f32x4 acc[4][4] = {};

  const int arow = tid >> 3;          // 0..31
  const int acb  = (tid & 7) << 4;    // byte col 0..112

#pragma unroll
  for (int s = 0; s < 4; ++s) {
    const int k0 = s * BK;
    // stage A
#pragma unroll
    for (int p = 0; p < 4; ++p) {
      int row = p * 32 + arow;
      int grow = m0 + row; if (grow >= M_NODES) grow = M_NODES - 1;
      int gcb = acb ^ ((row & 7) << 4);
      gload_lds16(h + (size_t)grow * D + k0 + (gcb >> 1), As + row * BK + (acb >> 1));
    }
    // stage B (Bt is [512][256], n-major)
#pragma unroll
    for (int p = 0; p < 4; ++p) {
      int row = p * 32 + arow;
      int gn = n0 + row;
      int gcb = acb ^ ((row & 7) << 4);
      gload_lds16(Bt + (size_t)gn * D + k0 + (gcb >> 1), Bs + row * BK + (acb >> 1));
    }
    __syncthreads();
#pragma unroll
    for (int kk = 0; kk < 2; ++kk) {
      bf16x8 af[4], bfr[4];
#pragma unroll
      for (int mi = 0; mi < 4; ++mi) {
        int row = wr * 64 + mi * 16 + lrow;
        int off = row * 128 + ((kk * 64 + lhi * 16) ^ ((row & 7) << 4));
        af[mi] = *(const bf16x8*)((const char*)As + off);
      }
#pragma unroll
      for (int nj = 0; nj < 4; ++nj) {
        int row = wc * 64 + nj * 16 + lrow;
        int off = row * 128 + ((kk * 64 + lhi * 16) ^ ((row & 7) << 4));
        bfr[nj] = *(const bf16x8*)((const char*)Bs + off);
      }
#pragma unroll
      for (int mi = 0; mi < 4; ++mi)
#pragma unroll
        for (int nj = 0; nj < 4; ++nj)
          acc[mi][nj] = __builtin_amdgcn_mfma_f32_16x16x32_bf16(af[mi], bfr[nj], acc[mi][nj], 0, 0, 0);
    }
    __syncthreads();
  }

  // epilogue: C/D map col=lane&15, row=(lane>>4)*4+reg
#pragma unroll
  for (int mi = 0; mi < 4; ++mi) {
#pragma unroll
    for (int nj = 0; nj < 4; ++nj) {
      int gc = n0 + wc * 64 + nj * 16 + lrow;
#pragma unroll
      for (int r = 0; r < 4; ++r) {
        int grow = m0 + wr * 64 + mi * 16 + lhi * 4 + r;
        if (grow < M_NODES)
          outAB[(size_t)grow * D2 + gc] = (ushort)f2bf(acc[mi][nj][r]);
      }
    }
  }
}

// ---------------- SpMM + selfterm + BN stats (max-TLP: 1 row-pair per wave) ----------------
// Wave w owns rows {2w, 2w+1}: lanes 0-31 -> row 2w, lanes 32-63 -> row 2w+1,
// each lane covers 16B (8 bf16 cols). No row loop: each wave issues its ~5
// gathers and dies; ~25-32 resident waves/CU at mixed pipeline phases keep
// the miss pipeline full. Metadata: one lane-parallel uint2 load, shfl
// broadcast (full wave active at every shfl).
__global__ __launch_bounds__(SPMM_TPB)
void spmm_kernel(ushort* __restrict__ AB, const int* __restrict__ rp,
                 const uint2* __restrict__ emeta, float* __restrict__ stats) {
  __shared__ float sstats[2 * D];
  for (int i = threadIdx.x; i < 2 * D; i += SPMM_TPB) sstats[i] = 0.f;
  __syncthreads();

  const int l  = threadIdx.x & 63;
  const int wv = threadIdx.x >> 6;              // 0..15
  const int hl = l >> 5, lc = l & 31;
  const int pair = blockIdx.x * (SPMM_TPB / 64) + wv;   // 0..49999 exact
  const int row  = pair * 2 + hl;

  int myrp = (l < 3) ? rp[pair * 2 + l] : 0;
  const int lo  = __shfl(myrp, 0);
  const int mid = __shfl(myrp, 1);
  const int end = __shfl(myrp, 2);
  const int ebase = lo, ecnt = end - lo;
  const int e0  = hl ? mid : lo;
  const int d0 = mid - lo, d1 = end - mid;
  const int deg = hl ? d1 : d0;
  const int degmax = (d0 > d1) ? d0 : d1;

  uint2 mymeta = {0u, 0u};
  if (l < ecnt) mymeta = emeta[ebase + l];      // one 8B load covers <=64 edges

  // selfterm prefetch (independent of gathers)
  const uint4 st = *(const uint4*)(AB + (size_t)row * D2 + D + lc * 8);

  float a[8] = {};
  for (int b = 0; b < degmax; b += 4) {         // wave-uniform bound
    float vv[4]; uint4 sp[4];
#pragma unroll
    for (int j = 0; j < 4; ++j) {
      int ej = b + j;
      int ecl = (ej < deg) ? ej : ((deg > 0) ? deg - 1 : 0);  // clamp: dup gather (cache hit)
      int slot = e0 - ebase + ecl;
      int sl = slot & 63;
      int c   = __shfl((int)mymeta.x, sl);                     // full wave active
      float v = __shfl(__uint_as_float(mymeta.y), sl);
      if (slot >= 64 && ej < deg) {             // >64 edges in a pair: ~never
        uint2 m = emeta[e0 + ecl]; c = (int)m.x; v = __uint_as_float(m.y);
      }
      vv[j] = (ej < deg) ? v : 0.f;
      sp[j] = *(const uint4*)(AB + (size_t)c * D2 + lc * 8);
    }
#pragma unroll
    for (int j = 0; j < 4; ++j) {
      a[0] += vv[j] * bf2f(sp[j].x & 0xffff);
      a[1] += vv[j] * bf2f(sp[j].x >> 16);
      a[2] += vv[j] * bf2f(sp[j].y & 0xffff);
      a[3] += vv[j] * bf2f(sp[j].y >> 16);
      a[4] += vv[j] * bf2f(sp[j].z & 0xffff);
      a[5] += vv[j] * bf2f(sp[j].z >> 16);
      a[6] += vv[j] * bf2f(sp[j].w & 0xffff);
      a[7] += vv[j] * bf2f(sp[j].w >> 16);
    }
  }

  // self term + write-back (cols 256..511 of own row)
  a[0] += bf2f(st.x & 0xffff); a[1] += bf2f(st.x >> 16);
  a[2] += bf2f(st.y & 0xffff); a[3] += bf2f(st.y >> 16);
  a[4] += bf2f(st.z & 0xffff); a[5] += bf2f(st.z >> 16);
  a[6] += bf2f(st.w & 0xffff); a[7] += bf2f(st.w >> 16);

  uint4 o;
  o.x = f2bf(a[0]) | (f2bf(a[1]) << 16);
  o.y = f2bf(a[2]) | (f2bf(a[3]) << 16);
  o.z = f2bf(a[4]) | (f2bf(a[5]) << 16);
  o.w = f2bf(a[6]) | (f2bf(a[7]) << 16);
  *(uint4*)(AB + (size_t)row * D2 + D + lc * 8) = o;

  // stats: cross-half shfl reduce (halves share columns), then LDS, then global.
  const int c0 = lc * 8;
#pragma unroll
  for (int k = 0; k < 8; ++k) {
    float a2 = a[k] * a[k];
    float sk = a[k] + __shfl_xor(a[k], 32);
    float qk = a2   + __shfl_xor(a2,   32);
    if (hl == 0) {
      atomicAdd(&sstats[c0 + k], sk);
      atomicAdd(&sstats[D + c0 + k], qk);
    }
  }
  __syncthreads();
  if (threadIdx.x < 2 * D)
    atomicAdd(&stats[threadIdx.x], sstats[threadIdx.x]);  // 3125 RMWs/address
}

// ---------------- fused BN finalize + normalize + ReLU ----------------
template<bool LAST>
__global__ void norm_kernel(const ushort* __restrict__ AB, const float* __restrict__ stats,
                            const float* __restrict__ gamma, const float* __restrict__ beta,
                            ushort* __restrict__ hout, float* __restrict__ out) {
  const int cs = threadIdx.x & 31;
  const int rr = threadIdx.x >> 5;   // 0..7
  const int c0 = cs * 8;

  float sc[8], sh[8];
#pragma unroll
  for (int k = 0; k < 8; ++k) {
    float mean = stats[c0 + k] * (1.0f / M_NODES);
    float var  = stats[D + c0 + k] * (1.0f / M_NODES) - mean * mean;
    float rstd = rsqrtf(var + 1e-5f);
    float g = gamma[c0 + k];
    sc[k] = g * rstd;
    sh[k] = beta[c0 + k] - mean * sc[k];
  }

  const int r0 = blockIdx.x * 64;
#pragma unroll
  for (int rb = 0; rb < 8; ++rb) {
    int r = r0 + rb * 8 + rr;
    if (r >= M_NODES) break;
    const uint4 u = *(const uint4*)(AB + (size_t)r * D2 + D + c0);
    float f[8];
    f[0] = bf2f(u.x & 0xffff); f[1] = bf2f(u.x >> 16);
    f[2] = bf2f(u.y & 0xffff); f[3] = bf2f(u.y >> 16);
    f[4] = bf2f(u.z & 0xffff); f[5] = bf2f(u.z >> 16);
    f[6] = bf2f(u.w & 0xffff); f[7] = bf2f(u.w >> 16);
#pragma unroll
    for (int k = 0; k < 8; ++k) f[k] = fmaxf(f[k] * sc[k] + sh[k], 0.f);
    if (LAST) {
      float4 r0v = { f[0], f[1], f[2], f[3] };
      float4 r1v = { f[4], f[5], f[6], f[7] };
      *(float4*)(out + (size_t)r * D2 + c0) = r0v;
      *(float4*)(out + (size_t)r * D2 + c0 + 4) = r1v;
    } else {
      uint4 o;
      o.x = f2bf(f[0]) | (f2bf(f[1]) << 16);
      o.y = f2bf(f[2]) | (f2bf(f[3]) << 16);
      o.z = f2bf(f[4]) | (f2bf(f[5]) << 16);
      o.w = f2bf(f[6]) | (f2bf(f[7]) << 16);
      *(uint4*)(hout + (size_t)r * D + c0) = o;
    }
  }
}

// ---------------- launch ----------------
extern "C" void kernel_launch(void* const* d_in, const int* in_sizes, int n_in,
                              void* d_out, int out_size, void* d_ws, size_t ws_size,
                              hipStream_t stream) {
  const float* x      = (const float*)d_in[0];
  const float* vals   = (const float*)d_in[1];
  const float* W      = (const float*)d_in[2];
  const float* SW     = (const float*)d_in[3];
  const float* gammas = (const float*)d_in[4];
  const float* betas  = (const float*)d_in[5];
  const int*   rows   = (const int*)d_in[6];
  const int*   cols   = (const int*)d_in[7];
  float* out = (float*)d_out;

  char* ws = (char*)d_ws;
  size_t off = 0;
  auto alloc = [&](size_t bytes) {
    void* p = ws + off;
    off = (off + bytes + 255) & ~(size_t)255;
    return p;
  };
  ushort* h     = (ushort*)alloc((size_t)M_NODES * D * 2);
  ushort* AB    = (ushort*)alloc((size_t)M_NODES * D2 * 2);
  ushort* Bt    = (ushort*)alloc((size_t)NLAYERS * D2 * D * 2);
  int*   rp     = (int*)alloc((M_NODES + 1) * 4);
  int*   cursor = (int*)alloc((M_NODES + 1) * 4);
  uint2* emeta  = (uint2*)alloc((size_t)NE * 8);
  int*   bsum   = (int*)alloc(512);
  int*   boff   = (int*)alloc(512);
  float* stats  = (float*)alloc(NLAYERS * 2 * D * 4);

  hipMemsetAsync(cursor, 0, (size_t)M_NODES * 4, stream);  // counts
  hipMemsetAsync(stats, 0, (size_t)NLAYERS * 2 * D * 4, stream);

  hist_kernel<<<(NE + 255) / 256, 256, 0, stream>>>(rows, cursor);
  scan1_kernel<<<98, 256, 0, stream>>>(cursor, rp, bsum);
  scan2_kernel<<<1, 128, 0, stream>>>(bsum, boff);
  scan3_kernel<<<(M_NODES + 256) / 256, 256, 0, stream>>>(rp, boff, cursor);
  scatter_kernel<<<(NE + 255) / 256, 256, 0, stream>>>(rows, cols, vals, cursor, emeta);

  prep_x_kernel<<<(M_NODES * D / 4) / 256, 256, 0, stream>>>(x, h, out);
  conv_w_kernel<<<(NLAYERS * D2 * D) / 256, 256, 0, stream>>>(W, SW, Bt);

  const int norm_blocks = (M_NODES + 63) / 64;
  for (int lyr = 0; lyr < NLAYERS; ++lyr) {
    gemm_kernel<<<dim3((M_NODES + BM - 1) / BM, D2 / BN), 256, 0, stream>>>(
        h, Bt + (size_t)lyr * D2 * D, AB);
    spmm_kernel<<<SPMM_GRID, SPMM_TPB, 0, stream>>>(AB, rp, emeta,
                                                    stats + (size_t)lyr * 2 * D);
    if (lyr < NLAYERS - 1)
      norm_kernel<false><<<norm_blocks, 256, 0, stream>>>(
          AB, stats + (size_t)lyr * 2 * D, gammas + lyr * D, betas + lyr * D, h, nullptr);
    else
      norm_kernel<true><<<norm_blocks, 256, 0, stream>>>(
          AB, stats + (size_t)lyr * 2 * D, gammas + lyr * D, betas + lyr * D, nullptr, out);
  }
}

// Round 7
// 712.037 us; speedup vs baseline: 1.6074x; 1.6074x over previous
//
#include <hip/hip_runtime.h>
#include <hip/hip_bf16.h>
#include <stdint.h>

#define M_NODES 100000
#define NE      300000
#define D       256
#define D2      512
#define NLAYERS 4

#define SPMM_CHUNK 16

typedef float  f32x4  __attribute__((ext_vector_type(4)));
typedef __bf16 bf16x8 __attribute__((ext_vector_type(8)));

static __device__ __forceinline__ float bf2f(uint32_t u) {
  union { uint32_t i; float f; } v; v.i = u << 16; return v.f;
}
static __device__ __forceinline__ uint32_t f2bf(float f) {
  union { float f; uint32_t i; } v; v.f = f;
  return (v.i + 0x7fffu + ((v.i >> 16) & 1u)) >> 16;
}
static __device__ __forceinline__ void gload_lds16(const void* g, void* l) {
  __builtin_amdgcn_global_load_lds((const __attribute__((address_space(1))) uint32_t*)g,
                                   (__attribute__((address_space(3))) uint32_t*)l, 16, 0, 0);
}

// ---------------- CSR build ----------------
__global__ void hist_kernel(const int* __restrict__ rows, int* __restrict__ counts) {
  int e = blockIdx.x * 256 + threadIdx.x;
  if (e < NE) atomicAdd(&counts[rows[e]], 1);
}

__global__ void scan1_kernel(const int* __restrict__ counts, int* __restrict__ rp,
                             int* __restrict__ bsum) {
  __shared__ int sd[256];
  int tid = threadIdx.x;
  int base = blockIdx.x * 1024 + tid * 4;
  int v0 = (base + 0 < M_NODES) ? counts[base + 0] : 0;
  int v1 = (base + 1 < M_NODES) ? counts[base + 1] : 0;
  int v2 = (base + 2 < M_NODES) ? counts[base + 2] : 0;
  int v3 = (base + 3 < M_NODES) ? counts[base + 3] : 0;
  int tsum = v0 + v1 + v2 + v3;
  sd[tid] = tsum; __syncthreads();
  for (int off = 1; off < 256; off <<= 1) {
    int x = sd[tid];
    if (tid >= off) x += sd[tid - off];
    __syncthreads(); sd[tid] = x; __syncthreads();
  }
  int excl = sd[tid] - tsum;
  if (base + 0 < M_NODES) rp[base + 0] = excl; excl += v0;
  if (base + 1 < M_NODES) rp[base + 1] = excl; excl += v1;
  if (base + 2 < M_NODES) rp[base + 2] = excl; excl += v2;
  if (base + 3 < M_NODES) rp[base + 3] = excl;
  if (tid == 255) bsum[blockIdx.x] = sd[255];
}

__global__ void scan2_kernel(const int* __restrict__ bsum, int* __restrict__ boff) {
  __shared__ int sd[128];
  int tid = threadIdx.x;
  int v = (tid < 98) ? bsum[tid] : 0;
  sd[tid] = v; __syncthreads();
  for (int off = 1; off < 128; off <<= 1) {
    int x = sd[tid];
    if (tid >= off) x += sd[tid - off];
    __syncthreads(); sd[tid] = x; __syncthreads();
  }
  if (tid < 98) boff[tid] = sd[tid] - v;
}

__global__ void scan3_kernel(int* __restrict__ rp, const int* __restrict__ boff,
                             int* __restrict__ cursor) {
  int i = blockIdx.x * 256 + threadIdx.x;
  if (i > M_NODES) return;
  int v = (i < M_NODES) ? rp[i] + boff[i >> 10] : NE;
  rp[i] = v;
  if (i < M_NODES) cursor[i] = v;
}

// emeta[p] = { col, val bits } interleaved: one 8B load per metadata slot.
__global__ void scatter_kernel(const int* __restrict__ rows, const int* __restrict__ cols,
                               const float* __restrict__ vals, int* __restrict__ cursor,
                               uint2* __restrict__ emeta) {
  int e = blockIdx.x * 256 + threadIdx.x;
  if (e >= NE) return;
  int r = rows[e];
  int p = atomicAdd(&cursor[r], 1);
  uint2 m; m.x = (uint32_t)cols[e]; m.y = __float_as_uint(vals[e]);
  emeta[p] = m;
}

// ---------------- x prep: f32 copy into out right half only ----------------
__global__ void prep_x_kernel(const float* __restrict__ x, float* __restrict__ out) {
  size_t idx = (size_t)blockIdx.x * 256 + threadIdx.x;  // M*D/4 threads
  size_t i = idx >> 6; int c = (int)(idx & 63) * 4;
  float4 v = *(const float4*)(x + i * D + c);
  *(float4*)(out + i * D2 + D + c) = v;
}

// Bt[layer][n][k] = bf16( n<256 ? W[layer][k][n] : SW[layer][k][n-256] )
__global__ void conv_w_kernel(const float* __restrict__ W, const float* __restrict__ SW,
                              ushort* __restrict__ Bt) {
  int idx = blockIdx.x * 256 + threadIdx.x;  // 4*512*256 = 524288
  if (idx >= NLAYERS * D2 * D) return;
  int k = idx & (D - 1);
  int n = (idx >> 8) & (D2 - 1);
  int layer = idx >> 17;
  float v = (n < D) ? W[(size_t)layer * D * D + k * D + n]
                    : SW[(size_t)layer * D * D + k * D + (n - D)];
  Bt[idx] = (ushort)f2bf(v);
}

// BN finalize: scale/shift for on-the-fly normalization in the next GEMM.
__global__ void bn_fin_kernel(const float* __restrict__ stats, const float* __restrict__ gamma,
                              const float* __restrict__ beta, float* __restrict__ ss) {
  int c = threadIdx.x;
  float mean = stats[c] * (1.0f / M_NODES);
  float var  = stats[D + c] * (1.0f / M_NODES) - mean * mean;
  float rstd = rsqrtf(var + 1e-5f);
  float sc = gamma[c] * rstd;
  ss[c] = sc;
  ss[D + c] = beta[c] - mean * sc;
}

// ---------------- GEMM: A[M,256] x Bt[512,256] -> AB [M,512](bf16) ----------------
// MODE 0: A = x (f32, layer 0), reg-staged with f2bf.
// MODE 1: A = relu(P*sc+sh) (P = pre-BN bf16 from prev spmm), reg-staged fused norm.
#define BM 128
#define BN 128
#define BK 64

template<int MODE>
__global__ __launch_bounds__(256, 2)
void gemm_kernel(const float* __restrict__ x, const ushort* __restrict__ P,
                 const float* __restrict__ ss, const ushort* __restrict__ Bt,
                 ushort* __restrict__ outAB) {
  __shared__ __align__(16) ushort As[BM * BK];  // [128][64] swizzled rows
  __shared__ __align__(16) ushort Bs[BN * BK];
  const int tid = threadIdx.x;
  const int m0 = blockIdx.x * BM;
  const int n0 = blockIdx.y * BN;
  const int wv = tid >> 6, l = tid & 63;
  const int wr = wv >> 1, wc = wv & 1;
  const int lrow = l & 15, lhi = l >> 4;

  f32x4 acc[4][4] = {};

  const int arow = tid >> 3;          // 0..31
  const int acb  = (tid & 7) << 4;    // byte col 0..112
  const int acol = acb >> 1;          // element col 0..56

#pragma unroll
  for (int s = 0; s < 4; ++s) {
    const int k0 = s * BK;
    // per-s scale/shift for this thread's 8 columns (MODE 1)
    float4 sc0, sc1, sh0, sh1;
    if (MODE == 1) {
      sc0 = *(const float4*)(ss + k0 + acol);
      sc1 = *(const float4*)(ss + k0 + acol + 4);
      sh0 = *(const float4*)(ss + D + k0 + acol);
      sh1 = *(const float4*)(ss + D + k0 + acol + 4);
    }
    // stage A (reg-staged, normalize/convert, swizzled ds_write)
#pragma unroll
    for (int p = 0; p < 4; ++p) {
      int row = p * 32 + arow;
      int grow = m0 + row; if (grow >= M_NODES) grow = M_NODES - 1;
      float f[8];
      if (MODE == 0) {
        float4 v0 = *(const float4*)(x + (size_t)grow * D + k0 + acol);
        float4 v1 = *(const float4*)(x + (size_t)grow * D + k0 + acol + 4);
        f[0] = v0.x; f[1] = v0.y; f[2] = v0.z; f[3] = v0.w;
        f[4] = v1.x; f[5] = v1.y; f[6] = v1.z; f[7] = v1.w;
      } else {
        uint4 u = *(const uint4*)(P + (size_t)grow * D + k0 + acol);
        f[0] = fmaxf(bf2f(u.x & 0xffff) * sc0.x + sh0.x, 0.f);
        f[1] = fmaxf(bf2f(u.x >> 16)    * sc0.y + sh0.y, 0.f);
        f[2] = fmaxf(bf2f(u.y & 0xffff) * sc0.z + sh0.z, 0.f);
        f[3] = fmaxf(bf2f(u.y >> 16)    * sc0.w + sh0.w, 0.f);
        f[4] = fmaxf(bf2f(u.z & 0xffff) * sc1.x + sh1.x, 0.f);
        f[5] = fmaxf(bf2f(u.z >> 16)    * sc1.y + sh1.y, 0.f);
        f[6] = fmaxf(bf2f(u.w & 0xffff) * sc1.z + sh1.z, 0.f);
        f[7] = fmaxf(bf2f(u.w >> 16)    * sc1.w + sh1.w, 0.f);
      }
      uint4 o;
      o.x = f2bf(f[0]) | (f2bf(f[1]) << 16);
      o.y = f2bf(f[2]) | (f2bf(f[3]) << 16);
      o.z = f2bf(f[4]) | (f2bf(f[5]) << 16);
      o.w = f2bf(f[6]) | (f2bf(f[7]) << 16);
      *(uint4*)((char*)As + row * 128 + (acb ^ ((row & 7) << 4))) = o;
    }
    // stage B via global_load_lds (pre-swizzled source)
#pragma unroll
    for (int p = 0; p < 4; ++p) {
      int row = p * 32 + arow;
      int gn = n0 + row;
      int gcb = acb ^ ((row & 7) << 4);
      gload_lds16(Bt + (size_t)gn * D + k0 + (gcb >> 1), Bs + row * BK + (acb >> 1));
    }
    __syncthreads();
#pragma unroll
    for (int kk = 0; kk < 2; ++kk) {
      bf16x8 af[4], bfr[4];
#pragma unroll
      for (int mi = 0; mi < 4; ++mi) {
        int row = wr * 64 + mi * 16 + lrow;
        int off = row * 128 + ((kk * 64 + lhi * 16) ^ ((row & 7) << 4));
        af[mi] = *(const bf16x8*)((const char*)As + off);
      }
#pragma unroll
      for (int nj = 0; nj < 4; ++nj) {
        int row = wc * 64 + nj * 16 + lrow;
        int off = row * 128 + ((kk * 64 + lhi * 16) ^ ((row & 7) << 4));
        bfr[nj] = *(const bf16x8*)((const char*)Bs + off);
      }
#pragma unroll
      for (int mi = 0; mi < 4; ++mi)
#pragma unroll
        for (int nj = 0; nj < 4; ++nj)
          acc[mi][nj] = __builtin_amdgcn_mfma_f32_16x16x32_bf16(af[mi], bfr[nj], acc[mi][nj], 0, 0, 0);
    }
    __syncthreads();
  }

  // epilogue: C/D map col=lane&15, row=(lane>>4)*4+reg
#pragma unroll
  for (int mi = 0; mi < 4; ++mi) {
#pragma unroll
    for (int nj = 0; nj < 4; ++nj) {
      int gc = n0 + wc * 64 + nj * 16 + lrow;
#pragma unroll
      for (int r = 0; r < 4; ++r) {
        int grow = m0 + wr * 64 + mi * 16 + lhi * 4 + r;
        if (grow < M_NODES)
          outAB[(size_t)grow * D2 + gc] = (ushort)f2bf(acc[mi][nj][r]);
      }
    }
  }
}

// ---------------- SpMM + selfterm + BN stats (round-2 structure) ----------------
// Wave owns a 16-row chunk; all 64 lanes on one row (4 cols/lane, 8B gathers);
// chunk metadata (<=128 edges) reg-preloaded, shfl-broadcast (wave-uniform loop
// bounds); batch-4 gathers in flight. Reads AB (gemm output), writes pre-BN
// out to P [M,256]. launch_bounds(256,8): ~32 waves/CU for gather MLP.
__global__ __launch_bounds__(256, 8)
void spmm_kernel(const ushort* __restrict__ AB, ushort* __restrict__ P,
                 const int* __restrict__ rp, const uint2* __restrict__ emeta,
                 float* __restrict__ stats) {
  __shared__ float sstats[2 * D];
  for (int i = threadIdx.x; i < 2 * D; i += 256) sstats[i] = 0.f;
  __syncthreads();

  const int wv = threadIdx.x >> 6, l = threadIdx.x & 63;
  const int wave = blockIdx.x * 4 + wv;
  const int row0 = wave * SPMM_CHUNK;

  float s0 = 0, s1 = 0, s2 = 0, s3 = 0, q0 = 0, q1 = 0, q2 = 0, q3 = 0;

  if (row0 < M_NODES) {
    const int nrows = (M_NODES - row0 < SPMM_CHUNK) ? (M_NODES - row0) : SPMM_CHUNK;
    int myrp = (l <= nrows) ? rp[row0 + l] : 0;
    const int ebase = __shfl(myrp, 0);
    const int ecnt  = __shfl(myrp, nrows) - ebase;
    uint2 m0 = {0u, 0u}, m1 = {0u, 0u};
    if (l < ecnt)      m0 = emeta[ebase + l];
    if (64 + l < ecnt) m1 = emeta[ebase + 64 + l];

    for (int t = 0; t < nrows; ++t) {
      const int i = row0 + t;
      const int e0 = __shfl(myrp, t);
      const int e1 = __shfl(myrp, t + 1);
      const int deg = e1 - e0;

      const ushort4 st = *(const ushort4*)(AB + (size_t)i * D2 + D + 4 * l);
      float a0 = bf2f(st.x), a1 = bf2f(st.y), a2 = bf2f(st.z), a3 = bf2f(st.w);

      for (int b = 0; b < deg; b += 4) {
        float vv[4]; ushort4 sp[4];
#pragma unroll
        for (int j = 0; j < 4; ++j) {
          int ej = b + j;
          int ecl = (ej < deg) ? ej : (deg - 1);   // clamp: dup gather (cache hit)
          int slot = e0 - ebase + ecl;
          int sl = slot & 63;
          int cA = __shfl((int)m0.x, sl);
          int cB = __shfl((int)m1.x, sl);
          float vA = __shfl(__uint_as_float(m0.y), sl);
          float vB = __shfl(__uint_as_float(m1.y), sl);
          int   c = (slot < 64) ? cA : cB;
          float v = (slot < 64) ? vA : vB;
          if (slot >= 128 && ej < deg) {           // statistically unreachable
            uint2 m = emeta[e0 + ecl]; c = (int)m.x; v = __uint_as_float(m.y);
          }
          vv[j] = (ej < deg) ? v : 0.f;
          sp[j] = *(const ushort4*)(AB + (size_t)c * D2 + 4 * l);
        }
#pragma unroll
        for (int j = 0; j < 4; ++j) {
          a0 += vv[j] * bf2f(sp[j].x); a1 += vv[j] * bf2f(sp[j].y);
          a2 += vv[j] * bf2f(sp[j].z); a3 += vv[j] * bf2f(sp[j].w);
        }
      }

      ushort4 o;
      o.x = (ushort)f2bf(a0); o.y = (ushort)f2bf(a1);
      o.z = (ushort)f2bf(a2); o.w = (ushort)f2bf(a3);
      *(ushort4*)(P + (size_t)i * D + 4 * l) = o;
      s0 += a0; q0 += a0 * a0; s1 += a1; q1 += a1 * a1;
      s2 += a2; q2 += a2 * a2; s3 += a3; q3 += a3 * a3;
    }
  }

  const int c0 = 4 * l;
  atomicAdd(&sstats[c0 + 0], s0); atomicAdd(&sstats[c0 + 1], s1);
  atomicAdd(&sstats[c0 + 2], s2); atomicAdd(&sstats[c0 + 3], s3);
  atomicAdd(&sstats[D + c0 + 0], q0); atomicAdd(&sstats[D + c0 + 1], q1);
  atomicAdd(&sstats[D + c0 + 2], q2); atomicAdd(&sstats[D + c0 + 3], q3);
  __syncthreads();
  atomicAdd(&stats[threadIdx.x], sstats[threadIdx.x]);
  atomicAdd(&stats[D + threadIdx.x], sstats[D + threadIdx.x]);
}

// ---------------- last-layer BN finalize + normalize + ReLU -> out f32 ----------------
__global__ void norm_last_kernel(const ushort* __restrict__ P, const float* __restrict__ stats,
                                 const float* __restrict__ gamma, const float* __restrict__ beta,
                                 float* __restrict__ out) {
  const int cs = threadIdx.x & 31;
  const int rr = threadIdx.x >> 5;   // 0..7
  const int c0 = cs * 8;

  float sc[8], sh[8];
#pragma unroll
  for (int k = 0; k < 8; ++k) {
    float mean = stats[c0 + k] * (1.0f / M_NODES);
    float var  = stats[D + c0 + k] * (1.0f / M_NODES) - mean * mean;
    float rstd = rsqrtf(var + 1e-5f);
    float g = gamma[c0 + k];
    sc[k] = g * rstd;
    sh[k] = beta[c0 + k] - mean * sc[k];
  }

  const int r0 = blockIdx.x * 64;
#pragma unroll
  for (int rb = 0; rb < 8; ++rb) {
    int r = r0 + rb * 8 + rr;
    if (r >= M_NODES) break;
    const uint4 u = *(const uint4*)(P + (size_t)r * D + c0);
    float f[8];
    f[0] = bf2f(u.x & 0xffff); f[1] = bf2f(u.x >> 16);
    f[2] = bf2f(u.y & 0xffff); f[3] = bf2f(u.y >> 16);
    f[4] = bf2f(u.z & 0xffff); f[5] = bf2f(u.z >> 16);
    f[6] = bf2f(u.w & 0xffff); f[7] = bf2f(u.w >> 16);
#pragma unroll
    for (int k = 0; k < 8; ++k) f[k] = fmaxf(f[k] * sc[k] + sh[k], 0.f);
    float4 r0v = { f[0], f[1], f[2], f[3] };
    float4 r1v = { f[4], f[5], f[6], f[7] };
    *(float4*)(out + (size_t)r * D2 + c0) = r0v;
    *(float4*)(out + (size_t)r * D2 + c0 + 4) = r1v;
  }
}

// ---------------- launch ----------------
extern "C" void kernel_launch(void* const* d_in, const int* in_sizes, int n_in,
                              void* d_out, int out_size, void* d_ws, size_t ws_size,
                              hipStream_t stream) {
  const float* x      = (const float*)d_in[0];
  const float* vals   = (const float*)d_in[1];
  const float* W      = (const float*)d_in[2];
  const float* SW     = (const float*)d_in[3];
  const float* gammas = (const float*)d_in[4];
  const float* betas  = (const float*)d_in[5];
  const int*   rows   = (const int*)d_in[6];
  const int*   cols   = (const int*)d_in[7];
  float* out = (float*)d_out;

  char* ws = (char*)d_ws;
  size_t off = 0;
  auto alloc = [&](size_t bytes) {
    void* p = ws + off;
    off = (off + bytes + 255) & ~(size_t)255;
    return p;
  };
  ushort* AB     = (ushort*)alloc((size_t)M_NODES * D2 * 2);   // 102.4 MB
  ushort* P      = (ushort*)alloc((size_t)M_NODES * D * 2);    // 51.2 MB
  ushort* Bt     = (ushort*)alloc((size_t)NLAYERS * D2 * D * 2);
  int*    rp     = (int*)alloc((M_NODES + 1) * 4);
  int*    cursor = (int*)alloc((M_NODES + 1) * 4);
  uint2*  emeta  = (uint2*)alloc((size_t)NE * 8);
  int*    bsum   = (int*)alloc(512);
  int*    boff   = (int*)alloc(512);
  float*  stats  = (float*)alloc(NLAYERS * 2 * D * 4);
  float*  ss     = (float*)alloc(2 * D * 4);

  hipMemsetAsync(cursor, 0, (size_t)M_NODES * 4, stream);  // counts
  hipMemsetAsync(stats, 0, (size_t)NLAYERS * 2 * D * 4, stream);

  hist_kernel<<<(NE + 255) / 256, 256, 0, stream>>>(rows, cursor);
  scan1_kernel<<<98, 256, 0, stream>>>(cursor, rp, bsum);
  scan2_kernel<<<1, 128, 0, stream>>>(bsum, boff);
  scan3_kernel<<<(M_NODES + 256) / 256, 256, 0, stream>>>(rp, boff, cursor);
  scatter_kernel<<<(NE + 255) / 256, 256, 0, stream>>>(rows, cols, vals, cursor, emeta);

  prep_x_kernel<<<(M_NODES * D / 4) / 256, 256, 0, stream>>>(x, out);
  conv_w_kernel<<<(NLAYERS * D2 * D) / 256, 256, 0, stream>>>(W, SW, Bt);

  const dim3 ggrid((M_NODES + BM - 1) / BM, D2 / BN);
  const int spmm_blocks = (M_NODES + SPMM_CHUNK * 4 - 1) / (SPMM_CHUNK * 4);
  for (int lyr = 0; lyr < NLAYERS; ++lyr) {
    if (lyr == 0)
      gemm_kernel<0><<<ggrid, 256, 0, stream>>>(x, nullptr, nullptr,
                                                Bt + (size_t)lyr * D2 * D, AB);
    else
      gemm_kernel<1><<<ggrid, 256, 0, stream>>>(nullptr, P, ss,
                                                Bt + (size_t)lyr * D2 * D, AB);
    spmm_kernel<<<spmm_blocks, 256, 0, stream>>>(AB, P, rp, emeta,
                                                 stats + (size_t)lyr * 2 * D);
    if (lyr < NLAYERS - 1)
      bn_fin_kernel<<<1, 256, 0, stream>>>(stats + (size_t)lyr * 2 * D,
                                           gammas + lyr * D, betas + lyr * D, ss);
    else
      norm_last_kernel<<<(M_NODES + 63) / 64, 256, 0, stream>>>(
          P, stats + (size_t)lyr * 2 * D, gammas + lyr * D, betas + lyr * D, out);
  }
}